// Round 2
// baseline (1453.786 us; speedup 1.0000x reference)
//
#include <hip/hip_runtime.h>
#include <hip/hip_bf16.h>

// Problem constants (from reference)
#define N_NODES 50000
#define N_EDGES 200000
#define BGRAPHS 512
#define F0c 78
#define H1c 10
#define HC1 780     // H1*F0
#define C2c 128
#define SEQc 1000
#define VOCABc 26
#define NFc 32
#define KWc 8
#define LOUTc 121
#define EMBc 128

static constexpr size_t alignup(size_t x) { return (x + 255) & ~size_t(255); }

// -------- workspace layout (bytes) --------
// Big region 0: hbuf bf16 [N,780] = 78,000,000 B. Dead after k_agg1.
//   Aliased afterwards by: hfin f32 [N,128] @ +0 (25.6 MB),
//   ord int [B,SEQ] @ +25.6 MB, Amat @ +27.6 MB, cvo @ +41.3 MB.
// Big region 1: out1 bf16 [N,780]. Dead after k_gemm2.
static constexpr size_t A_HBUF = 0;
static constexpr size_t A_OUT1 = alignup(A_HBUF + size_t(N_NODES)*HC1*2);
static constexpr size_t A_H2   = alignup(A_OUT1 + size_t(N_NODES)*HC1*2);
static constexpr size_t A_ALS1 = alignup(A_H2   + size_t(N_NODES)*C2c*4);
static constexpr size_t A_ALD1 = alignup(A_ALS1 + size_t(N_NODES)*H1c*4);
static constexpr size_t A_ALS2 = alignup(A_ALD1 + size_t(N_NODES)*H1c*4);
static constexpr size_t A_ALD2 = alignup(A_ALS2 + size_t(N_NODES)*4);
static constexpr size_t A_DEG  = alignup(A_ALD2 + size_t(N_NODES)*4);
static constexpr size_t A_OFFS = alignup(A_DEG  + size_t(N_NODES)*4);
static constexpr size_t A_CUR  = alignup(A_OFFS + size_t(N_NODES+1)*4);
static constexpr size_t A_CSRC = alignup(A_CUR  + size_t(N_NODES)*4);
static constexpr size_t A_G    = alignup(A_CSRC + size_t(N_EDGES+N_NODES)*4);
static constexpr size_t A_XC   = alignup(A_G    + size_t(BGRAPHS)*C2c*4);
static constexpr size_t A_Y1   = alignup(A_XC   + size_t(BGRAPHS)*256*4);
static constexpr size_t A_Y2   = alignup(A_Y1   + size_t(BGRAPHS)*1024*4);
static constexpr size_t A_BOFF = alignup(A_Y2   + size_t(BGRAPHS)*256*4);
static constexpr size_t A_END  = alignup(A_BOFF + size_t(BGRAPHS)*(VOCABc+1)*4);
// aliases inside hbuf region (valid only after k_agg1 has retired):
static constexpr size_t A_HFIN = 0;                                             // f32 [N,128] = 25,600,000
static constexpr size_t A_ORD  = alignup(A_HFIN + size_t(N_NODES)*C2c*4);       // int [B,SEQ]
static constexpr size_t A_AMAT = alignup(A_ORD  + size_t(BGRAPHS)*SEQc*4);      // f32 [B,32,26,8]
static constexpr size_t A_CVO  = alignup(A_AMAT + size_t(BGRAPHS)*NFc*VOCABc*KWc*4); // f32 [B,32,121]
static_assert(A_CVO + size_t(BGRAPHS)*NFc*LOUTc*4 <= size_t(N_NODES)*HC1*2, "alias overflow");
// A_END ~ 191.1 MB total

// -------- typed load/store helpers --------
__device__ __forceinline__ float ldf(const float* p) { return *p; }
__device__ __forceinline__ float ldf(const __hip_bfloat16* p) { return __bfloat162float(*p); }
__device__ __forceinline__ void stf(float* p, float v) { *p = v; }
__device__ __forceinline__ void stf(__hip_bfloat16* p, float v) { *p = __float2bfloat16(v); }

// ---------------- CSR build ----------------
__global__ void k_deginit(int* deg) {
    int i = blockIdx.x*256 + threadIdx.x;
    if (i < N_NODES) deg[i] = 1;   // self loop
}
__global__ void k_count(const int* __restrict__ ei, int* deg) {
    int i = blockIdx.x*256 + threadIdx.x;
    if (i < N_EDGES) atomicAdd(&deg[ei[N_EDGES + i]], 1);
}
// single-block exclusive scan of deg[0..n) -> off[0..n]
__global__ void k_scan(const int* __restrict__ deg, int* __restrict__ off, int n) {
    __shared__ int wsum[16];
    __shared__ int s_carry;
    int tid = threadIdx.x, lane = tid & 63, wid = tid >> 6;
    if (tid == 0) s_carry = 0;
    __syncthreads();
    for (int base = 0; base < n; base += 1024) {
        int i = base + tid;
        int v0 = (i < n) ? deg[i] : 0;
        int v = v0;
        for (int d = 1; d < 64; d <<= 1) { int t = __shfl_up(v, d, 64); if (lane >= d) v += t; }
        if (lane == 63) wsum[wid] = v;
        __syncthreads();
        if (wid == 0) {
            int w = (lane < 16) ? wsum[lane] : 0;
            for (int d = 1; d < 16; d <<= 1) { int t = __shfl_up(w, d, 64); if (lane >= d) w += t; }
            if (lane < 16) wsum[lane] = w;
        }
        __syncthreads();
        int wprev = (wid > 0) ? wsum[wid-1] : 0;
        int carry = s_carry;
        if (i < n) off[i] = carry + wprev + (v - v0);
        __syncthreads();
        if (tid == 0) s_carry = carry + wsum[15];
        __syncthreads();
    }
    if (tid == 0) off[n] = s_carry;
}
__global__ void k_copy(const int* __restrict__ off, int* cur) {
    int i = blockIdx.x*256 + threadIdx.x;
    if (i < N_NODES) cur[i] = off[i];
}
__global__ void k_fill(const int* __restrict__ ei, int* cur, int* __restrict__ csrc) {
    int i = blockIdx.x*256 + threadIdx.x;
    if (i < N_EDGES) {
        int s = ei[i], d = ei[N_EDGES + i];
        int p = atomicAdd(&cur[d], 1);
        csrc[p] = s;
    } else if (i < N_EDGES + N_NODES) {
        int n = i - N_EDGES;
        int p = atomicAdd(&cur[n], 1);
        csrc[p] = n;
    }
}

// ---------------- GEMM1: [N,78]@[78,780] -> bf16 out ----------------
template<typename TO>
__global__ void k_gemm1(const float* __restrict__ x, const float* __restrict__ W,
                        TO* __restrict__ out) {
    __shared__ float xs[F0c*8];           // [k][r]
    int tid = threadIdx.x;
    int c = blockIdx.x*256 + tid;
    int r0 = blockIdx.y*8;                // 50000 = 8*6250 exact
    for (int i = tid; i < F0c*8; i += 256) {
        int k = i >> 3, r = i & 7;
        xs[i] = x[(size_t)(r0 + r)*F0c + k];
    }
    __syncthreads();
    if (c < HC1) {
        float acc[8] = {0,0,0,0,0,0,0,0};
        for (int k = 0; k < F0c; k++) {
            float w = W[(size_t)k*HC1 + c];
            #pragma unroll
            for (int r = 0; r < 8; r++) acc[r] += xs[k*8+r] * w;
        }
        #pragma unroll
        for (int r = 0; r < 8; r++) stf(&out[(size_t)(r0+r)*HC1 + c], acc[r]);
    }
}

// ---------------- GEMM2: [N,780](bf16)@[780,128] -> f32 ----------------
template<typename TI>
__global__ void k_gemm2(const TI* __restrict__ A, const float* __restrict__ W,
                        float* __restrict__ Cout) {
    __shared__ float as[30*33];           // [kk][row], padded
    int tid = threadIdx.x;
    int c = tid & 127, rh = tid >> 7;
    int r0 = blockIdx.x * 32;
    float acc[16];
    #pragma unroll
    for (int r = 0; r < 16; r++) acc[r] = 0.f;
    for (int kt = 0; kt < 26; kt++) {
        int k0 = kt * 30;
        for (int i = tid; i < 960; i += 256) {
            int row = i / 30, kk = i - row*30;
            int r = r0 + row;
            as[kk*33 + row] = (r < N_NODES) ? ldf(&A[(size_t)r*HC1 + k0 + kk]) : 0.f;
        }
        __syncthreads();
        for (int kk = 0; kk < 30; kk++) {
            float w = W[(size_t)(k0+kk)*C2c + c];
            #pragma unroll
            for (int r = 0; r < 16; r++) acc[r] += as[kk*33 + rh*16 + r] * w;
        }
        __syncthreads();
    }
    #pragma unroll
    for (int r = 0; r < 16; r++) {
        int row = r0 + rh*16 + r;
        if (row < N_NODES) Cout[(size_t)row*C2c + c] = acc[r];
    }
}

// ---------------- attention logit precompute ----------------
template<typename TI>
__global__ void k_att1(const TI* __restrict__ h, const float* __restrict__ a_src,
                       const float* __restrict__ a_dst, float* __restrict__ als,
                       float* __restrict__ ald) {
    int i = blockIdx.x*256 + threadIdx.x;
    if (i >= N_NODES*H1c) return;
    int n = i / H1c, hh = i - n*H1c;
    const TI* hp  = h + (size_t)n*HC1 + hh*F0c;
    const float* asv = a_src + hh*F0c;
    const float* adv = a_dst + hh*F0c;
    float s1 = 0.f, s2 = 0.f;
    for (int c = 0; c < F0c; c++) { float v = ldf(&hp[c]); s1 += v*asv[c]; s2 += v*adv[c]; }
    als[i] = s1; ald[i] = s2;
}
__global__ void k_att2(const float* __restrict__ h, const float* __restrict__ a_src,
                       const float* __restrict__ a_dst, float* __restrict__ als,
                       float* __restrict__ ald) {
    int n = blockIdx.x*256 + threadIdx.x;
    if (n >= N_NODES) return;
    const float* hp = h + (size_t)n*C2c;
    float s1 = 0.f, s2 = 0.f;
    for (int c = 0; c < C2c; c++) { float v = hp[c]; s1 += v*a_src[c]; s2 += v*a_dst[c]; }
    als[n] = s1; ald[n] = s2;
}

// ---------------- GAT aggregation: one wave per dst node ----------------
// ACT: 0=elu, 1=relu
template<typename TI, typename TO, int H, int C, int ACT>
__global__ void k_agg(const TI* __restrict__ hbuf, const float* __restrict__ als,
                      const float* __restrict__ ald, const int* __restrict__ offs,
                      const int* __restrict__ csrc, const float* __restrict__ bias,
                      TO* __restrict__ out) {
    int dn = blockIdx.x;
    int lane = threadIdx.x;      // 64
    int s = offs[dn], e = offs[dn+1];
    __shared__ float ms[H], dinv_s[H];
    if (lane < H) {
        float adv = ald[(size_t)dn*H + lane];
        float m = -1e30f;
        for (int j = s; j < e; j++) {
            int sj = csrc[j];
            float al = als[(size_t)sj*H + lane] + adv;
            al = (al >= 0.f) ? al : 0.2f*al;
            m = fmaxf(m, al);
        }
        float den = 0.f;
        for (int j = s; j < e; j++) {
            int sj = csrc[j];
            float al = als[(size_t)sj*H + lane] + adv;
            al = (al >= 0.f) ? al : 0.2f*al;
            den += __expf(al - m);
        }
        ms[lane] = m;
        dinv_s[lane] = 1.0f / (den + 1e-16f);
    }
    __syncthreads();
    for (int hh = 0; hh < H; hh++) {
        float m = ms[hh], dinv = dinv_s[hh];
        float adv = ald[(size_t)dn*H + hh];
        for (int cb = 0; cb < C; cb += 64) {
            int c = cb + lane;
            if (c < C) {
                float acc = 0.f;
                for (int j = s; j < e; j++) {
                    int sj = csrc[j];
                    float al = als[(size_t)sj*H + hh] + adv;
                    al = (al >= 0.f) ? al : 0.2f*al;
                    float alpha = __expf(al - m) * dinv;
                    acc += alpha * ldf(&hbuf[(size_t)sj*(H*C) + hh*C + c]);
                }
                float v = acc + bias[hh*C + c];
                if (ACT == 0) v = (v > 0.f) ? v : (__expf(v) - 1.f);
                else          v = fmaxf(v, 0.f);
                stf(&out[(size_t)dn*(H*C) + hh*C + c], v);
            }
        }
    }
}

// ---------------- global max pool (batch sorted) ----------------
__global__ void k_pool(const float* __restrict__ hf, const int* __restrict__ batch,
                       float* __restrict__ g) {
    int b = blockIdx.x, tid = threadIdx.x;    // 128
    __shared__ int se[2];
    if (tid < 2) {
        int key = b + tid;
        int lo = 0, hi = N_NODES;
        while (lo < hi) { int mid = (lo+hi) >> 1; if (batch[mid] < key) lo = mid+1; else hi = mid; }
        se[tid] = lo;
    }
    __syncthreads();
    int s = se[0], e = se[1];
    float m = -1e30f;
    for (int n = s; n < e; n++) m = fmaxf(m, hf[(size_t)n*C2c + tid]);
    g[b*C2c + tid] = m;
}
__global__ void k_fcg(const float* __restrict__ g, const float* __restrict__ W,
                      const float* __restrict__ bias, float* __restrict__ xc) {
    int b = blockIdx.x, tid = threadIdx.x;    // 128
    __shared__ float gs[C2c];
    gs[tid] = g[b*C2c + tid];
    __syncthreads();
    float acc = bias[tid];
    for (int k = 0; k < C2c; k++) acc += gs[k] * W[k*C2c + tid];
    xc[b*256 + tid] = fmaxf(acc, 0.f);
}

// ---------------- conv path: bucket targets by vocab ----------------
__global__ void k_bucket(const int* __restrict__ target, int* __restrict__ ordered,
                         int* __restrict__ boff) {
    int b = blockIdx.x, tid = threadIdx.x;    // 256
    __shared__ int cnt[VOCABc];
    __shared__ int offs[VOCABc+1];
    __shared__ int cur[VOCABc];
    if (tid < VOCABc) cnt[tid] = 0;
    __syncthreads();
    for (int i = tid; i < SEQc; i += 256) atomicAdd(&cnt[target[(size_t)b*SEQc + i]], 1);
    __syncthreads();
    if (tid == 0) { offs[0] = 0; for (int v = 0; v < VOCABc; v++) offs[v+1] = offs[v] + cnt[v]; }
    __syncthreads();
    if (tid < VOCABc) cur[tid] = offs[tid];
    if (tid < VOCABc+1) boff[b*(VOCABc+1) + tid] = offs[tid];
    __syncthreads();
    for (int i = tid; i < SEQc; i += 256) {
        int t = target[(size_t)b*SEQc + i];
        int p = atomicAdd(&cur[t], 1);
        ordered[(size_t)b*SEQc + p] = i;
    }
}
// A[b,o,t,k] = sum_{i: target[b,i]==t} conv_w[o,i,k]
__global__ void k_buildA(const float* __restrict__ convw, const int* __restrict__ ordered,
                         const int* __restrict__ boff, float* __restrict__ Amat) {
    int t = blockIdx.x, b = blockIdx.y;
    int tid = threadIdx.x;                // 256 = 32 o * 8 k
    int o = tid >> 3, k = tid & 7;
    int s = boff[b*(VOCABc+1) + t], e = boff[b*(VOCABc+1) + t + 1];
    const int* ord = ordered + (size_t)b*SEQc;
    float acc = 0.f;
    for (int j = s; j < e; j++) {
        int i = ord[j];
        acc += convw[((size_t)o*SEQc + i)*KWc + k];
    }
    Amat[(((size_t)b*NFc + o)*VOCABc + t)*KWc + k] = acc;
}
// conv[b,o,l] = relu(conv_b[o] + sum_{t,k} A[b,o,t,k]*emb[t,l+k])
__global__ void k_conv(const float* __restrict__ Amat, const float* __restrict__ emb,
                       const float* __restrict__ convb, float* __restrict__ convout) {
    int b = blockIdx.x, tid = threadIdx.x;    // 128
    __shared__ float embs[VOCABc*EMBc];       // 13.3 KB
    __shared__ float arow[VOCABc*KWc];        // 832 B
    for (int i = tid; i < VOCABc*EMBc; i += 128) embs[i] = emb[i];
    __syncthreads();
    for (int o = 0; o < NFc; o++) {
        for (int i = tid; i < VOCABc*KWc; i += 128)
            arow[i] = Amat[((size_t)b*NFc + o)*(VOCABc*KWc) + i];
        __syncthreads();
        if (tid < LOUTc) {
            float acc = convb[o];
            for (int t = 0; t < VOCABc; t++) {
                #pragma unroll
                for (int k = 0; k < KWc; k++) acc += arow[t*KWc + k] * embs[t*EMBc + tid + k];
            }
            convout[(size_t)b*(NFc*LOUTc) + o*LOUTc + tid] = fmaxf(acc, 0.f);
        }
        __syncthreads();
    }
}
__global__ void k_fcxt(const float* __restrict__ convout, const float* __restrict__ W,
                       const float* __restrict__ bias, float* __restrict__ xc) {
    int b = blockIdx.x, tid = threadIdx.x;    // 128
    __shared__ float cs[NFc*LOUTc];           // 15.5 KB
    for (int i = tid; i < NFc*LOUTc; i += 128) cs[i] = convout[(size_t)b*(NFc*LOUTc) + i];
    __syncthreads();
    float acc = bias[tid];
    for (int j = 0; j < NFc*LOUTc; j++) acc += cs[j] * W[(size_t)j*C2c + tid];
    xc[b*256 + 128 + tid] = acc;
}

// ---------------- head MLP ----------------
__global__ void k_fc1(const float* __restrict__ xc, const float* __restrict__ W,
                      const float* __restrict__ bias, float* __restrict__ y1) {
    int b = blockIdx.x, tid = threadIdx.x;    // 256
    __shared__ float xs[256];
    xs[tid] = xc[b*256 + tid];
    __syncthreads();
    float a0 = bias[tid], a1 = bias[tid+256], a2 = bias[tid+512], a3 = bias[tid+768];
    for (int k = 0; k < 256; k++) {
        float xk = xs[k];
        const float* wr = W + (size_t)k*1024;
        a0 += xk*wr[tid]; a1 += xk*wr[tid+256]; a2 += xk*wr[tid+512]; a3 += xk*wr[tid+768];
    }
    y1[(size_t)b*1024 + tid      ] = fmaxf(a0, 0.f);
    y1[(size_t)b*1024 + tid + 256] = fmaxf(a1, 0.f);
    y1[(size_t)b*1024 + tid + 512] = fmaxf(a2, 0.f);
    y1[(size_t)b*1024 + tid + 768] = fmaxf(a3, 0.f);
}
__global__ void k_fc2(const float* __restrict__ y1, const float* __restrict__ W,
                      const float* __restrict__ bias, float* __restrict__ y2) {
    int b = blockIdx.x, tid = threadIdx.x;    // 256
    __shared__ float ys[1024];
    for (int i = tid; i < 1024; i += 256) ys[i] = y1[(size_t)b*1024 + i];
    __syncthreads();
    float acc = bias[tid];
    for (int k = 0; k < 1024; k++) acc += ys[k] * W[(size_t)k*256 + tid];
    y2[b*256 + tid] = fmaxf(acc, 0.f);
}
__global__ void k_out(const float* __restrict__ y2, const float* __restrict__ ow,
                      const float* __restrict__ ob, float* __restrict__ out) {
    int b = blockIdx.x, lane = threadIdx.x;   // 64
    float p = 0.f;
    for (int c = lane; c < 256; c += 64) p += y2[b*256 + c] * ow[c];
    for (int d = 32; d > 0; d >>= 1) p += __shfl_xor(p, d, 64);
    if (lane == 0) out[b] = p + ob[0];
}

extern "C" void kernel_launch(void* const* d_in, const int* in_sizes, int n_in,
                              void* d_out, int out_size, void* d_ws, size_t ws_size,
                              hipStream_t stream) {
    (void)in_sizes; (void)n_in; (void)out_size;
    if (ws_size < A_END) return;   // diagnostic guard: numeric-fail (not crash) if ws too small

    const float* x       = (const float*)d_in[0];
    const int*   ei      = (const int*)  d_in[1];
    const int*   batch   = (const int*)  d_in[2];
    const int*   target  = (const int*)  d_in[3];
    const float* W1      = (const float*)d_in[4];
    const float* a_src1  = (const float*)d_in[5];
    const float* a_dst1  = (const float*)d_in[6];
    const float* b1      = (const float*)d_in[7];
    const float* W2      = (const float*)d_in[8];
    const float* a_src2  = (const float*)d_in[9];
    const float* a_dst2  = (const float*)d_in[10];
    const float* b2      = (const float*)d_in[11];
    const float* fcg_w   = (const float*)d_in[12];
    const float* fcg_b   = (const float*)d_in[13];
    const float* emb     = (const float*)d_in[14];
    const float* conv_w  = (const float*)d_in[15];
    const float* conv_b  = (const float*)d_in[16];
    const float* fcxt_w  = (const float*)d_in[17];
    const float* fcxt_b  = (const float*)d_in[18];
    const float* fc1_w   = (const float*)d_in[19];
    const float* fc1_b   = (const float*)d_in[20];
    const float* fc2_w   = (const float*)d_in[21];
    const float* fc2_b   = (const float*)d_in[22];
    const float* out_w   = (const float*)d_in[23];
    const float* out_b   = (const float*)d_in[24];

    char* wsb = (char*)d_ws;
    __hip_bfloat16* hbuf = (__hip_bfloat16*)(wsb + A_HBUF);
    __hip_bfloat16* out1 = (__hip_bfloat16*)(wsb + A_OUT1);
    float* h2    = (float*)(wsb + A_H2);
    float* als1  = (float*)(wsb + A_ALS1);
    float* ald1  = (float*)(wsb + A_ALD1);
    float* als2  = (float*)(wsb + A_ALS2);
    float* ald2  = (float*)(wsb + A_ALD2);
    int*   deg   = (int*)  (wsb + A_DEG);
    int*   offs  = (int*)  (wsb + A_OFFS);
    int*   cur   = (int*)  (wsb + A_CUR);
    int*   csrc  = (int*)  (wsb + A_CSRC);
    float* g     = (float*)(wsb + A_G);
    float* xc    = (float*)(wsb + A_XC);
    float* y1    = (float*)(wsb + A_Y1);
    float* y2    = (float*)(wsb + A_Y2);
    int*   boff  = (int*)  (wsb + A_BOFF);
    // aliases into the hbuf region (only touched after k_agg1 retires):
    float* hfin  = (float*)(wsb + A_HFIN);
    int*   ord   = (int*)  (wsb + A_ORD);
    float* Amat  = (float*)(wsb + A_AMAT);
    float* cvo   = (float*)(wsb + A_CVO);

    // CSR build (dst-grouped, self loops included via deg init = 1)
    k_deginit<<<(N_NODES+255)/256, 256, 0, stream>>>(deg);
    k_count  <<<(N_EDGES+255)/256, 256, 0, stream>>>(ei, deg);
    k_scan   <<<1, 1024, 0, stream>>>(deg, offs, N_NODES);
    k_copy   <<<(N_NODES+255)/256, 256, 0, stream>>>(offs, cur);
    k_fill   <<<(N_EDGES+N_NODES+255)/256, 256, 0, stream>>>(ei, cur, csrc);

    // GAT layer 1 (hbuf, out1 stored bf16)
    k_gemm1<__hip_bfloat16><<<dim3(4, N_NODES/8), 256, 0, stream>>>(x, W1, hbuf);
    k_att1<__hip_bfloat16><<<(N_NODES*H1c+255)/256, 256, 0, stream>>>(hbuf, a_src1, a_dst1, als1, ald1);
    k_agg<__hip_bfloat16, __hip_bfloat16, H1c, F0c, 0><<<N_NODES, 64, 0, stream>>>(
        hbuf, als1, ald1, offs, csrc, b1, out1);
    // ---- hbuf dead from here; its region is reused for hfin/ord/Amat/cvo ----

    // GAT layer 2
    k_gemm2<__hip_bfloat16><<<(N_NODES+31)/32, 256, 0, stream>>>(out1, W2, h2);
    k_att2 <<<(N_NODES+255)/256, 256, 0, stream>>>(h2, a_src2, a_dst2, als2, ald2);
    k_agg<float, float, 1, C2c, 1><<<N_NODES, 64, 0, stream>>>(
        h2, als2, ald2, offs, csrc, b2, hfin);

    // pool + fc_g1 -> xc[:, 0:128]
    k_pool<<<BGRAPHS, 128, 0, stream>>>(hfin, batch, g);
    k_fcg <<<BGRAPHS, 128, 0, stream>>>(g, fcg_w, fcg_b, xc);

    // conv path -> xc[:, 128:256]
    k_bucket<<<BGRAPHS, 256, 0, stream>>>(target, ord, boff);
    k_buildA<<<dim3(VOCABc, BGRAPHS), 256, 0, stream>>>(conv_w, ord, boff, Amat);
    k_conv  <<<BGRAPHS, 128, 0, stream>>>(Amat, emb, conv_b, cvo);
    k_fcxt  <<<BGRAPHS, 128, 0, stream>>>(cvo, fcxt_w, fcxt_b, xc);

    // head MLP
    k_fc1<<<BGRAPHS, 256, 0, stream>>>(xc, fc1_w, fc1_b, y1);
    k_fc2<<<BGRAPHS, 256, 0, stream>>>(y1, fc2_w, fc2_b, y2);
    k_out<<<BGRAPHS, 64, 0, stream>>>(y2, out_w, out_b, (float*)d_out);
}

// Round 3
// 1000.815 us; speedup vs baseline: 1.4526x; 1.4526x over previous
//
#include <hip/hip_runtime.h>
#include <hip/hip_bf16.h>

// Problem constants (from reference)
#define N_NODES 50000
#define N_EDGES 200000
#define BGRAPHS 512
#define F0c 78
#define H1c 10
#define HC1 780     // H1*F0
#define HSTR 800    // padded row stride (bf16 elems) for h1/out1, K-mult of 32
#define C2c 128
#define SEQc 1000
#define VOCABc 26
#define NFc 32
#define KWc 8
#define LOUTc 121
#define EMBc 128
#define KX 96       // padded K for gemm1 (78 -> 96)

typedef __attribute__((ext_vector_type(8))) short short8;
typedef __attribute__((ext_vector_type(4))) float f32x4;

static constexpr size_t alignup(size_t x) { return (x + 255) & ~size_t(255); }

// -------- workspace layout (bytes) --------
static constexpr size_t A_HBUF = 0;                                          // bf16 [N,800] = 80 MB
static constexpr size_t A_OUT1 = alignup(A_HBUF + size_t(N_NODES)*HSTR*2);   // bf16 [N,800] = 80 MB
static constexpr size_t A_H2   = alignup(A_OUT1 + size_t(N_NODES)*HSTR*2);   // f32  [N,128]
static constexpr size_t A_W2T  = alignup(A_H2   + size_t(N_NODES)*C2c*4);    // bf16 [128,800]
static constexpr size_t A_ALS1 = alignup(A_W2T  + size_t(C2c)*HSTR*2);
static constexpr size_t A_ALD1 = alignup(A_ALS1 + size_t(N_NODES)*H1c*4);
static constexpr size_t A_ALS2 = alignup(A_ALD1 + size_t(N_NODES)*H1c*4);
static constexpr size_t A_ALD2 = alignup(A_ALS2 + size_t(N_NODES)*4);
static constexpr size_t A_DEG  = alignup(A_ALD2 + size_t(N_NODES)*4);
static constexpr size_t A_OFFS = alignup(A_DEG  + size_t(N_NODES)*4);
static constexpr size_t A_CUR  = alignup(A_OFFS + size_t(N_NODES+1)*4);
static constexpr size_t A_CSRC = alignup(A_CUR  + size_t(N_NODES)*4);
static constexpr size_t A_G    = alignup(A_CSRC + size_t(N_EDGES+N_NODES)*4);
static constexpr size_t A_XC   = alignup(A_G    + size_t(BGRAPHS)*C2c*4);
static constexpr size_t A_Y1   = alignup(A_XC   + size_t(BGRAPHS)*256*4);
static constexpr size_t A_Y2   = alignup(A_Y1   + size_t(BGRAPHS)*1024*4);
static constexpr size_t A_BOFF = alignup(A_Y2   + size_t(BGRAPHS)*256*4);
static constexpr size_t A_END  = alignup(A_BOFF + size_t(BGRAPHS)*(VOCABc+1)*4);
// ~195.3 MB total

// aliases inside hbuf region (valid after k_agg1 retires; hbuf dead then):
static constexpr size_t A_HFIN = A_HBUF;                                        // f32 [N,128]
static constexpr size_t A_ORD  = alignup(A_HFIN + size_t(N_NODES)*C2c*4);
static constexpr size_t A_AMAT = alignup(A_ORD  + size_t(BGRAPHS)*SEQc*4);
static constexpr size_t A_CVO  = alignup(A_AMAT + size_t(BGRAPHS)*NFc*VOCABc*KWc*4);
static_assert(A_CVO + size_t(BGRAPHS)*NFc*LOUTc*4 <= size_t(N_NODES)*HSTR*2, "alias A overflow");
// aliases inside out1 region (valid until k_agg1 writes out1):
static constexpr size_t A_XPAD = A_OUT1;                                        // bf16 [N,96]
static constexpr size_t A_W1T  = alignup(A_XPAD + size_t(N_NODES)*KX*2);        // bf16 [784,96]
static_assert(A_W1T + size_t(784)*KX*2 - A_OUT1 <= size_t(N_NODES)*HSTR*2, "alias B overflow");

// -------- typed load/store helpers --------
__device__ __forceinline__ float ldf(const float* p) { return *p; }
__device__ __forceinline__ float ldf(const __hip_bfloat16* p) { return __bfloat162float(*p); }
__device__ __forceinline__ void stf(float* p, float v) { *p = v; }
__device__ __forceinline__ void stf(__hip_bfloat16* p, float v) { *p = __float2bfloat16(v); }

// ---------------- CSR build ----------------
__global__ void k_deginit(int* deg) {
    int i = blockIdx.x*256 + threadIdx.x;
    if (i < N_NODES) deg[i] = 1;   // self loop
}
__global__ void k_count(const int* __restrict__ ei, int* deg) {
    int i = blockIdx.x*256 + threadIdx.x;
    if (i < N_EDGES) atomicAdd(&deg[ei[N_EDGES + i]], 1);
}
__global__ void k_scan(const int* __restrict__ deg, int* __restrict__ off, int n) {
    __shared__ int wsum[16];
    __shared__ int s_carry;
    int tid = threadIdx.x, lane = tid & 63, wid = tid >> 6;
    if (tid == 0) s_carry = 0;
    __syncthreads();
    for (int base = 0; base < n; base += 1024) {
        int i = base + tid;
        int v0 = (i < n) ? deg[i] : 0;
        int v = v0;
        for (int d = 1; d < 64; d <<= 1) { int t = __shfl_up(v, d, 64); if (lane >= d) v += t; }
        if (lane == 63) wsum[wid] = v;
        __syncthreads();
        if (wid == 0) {
            int w = (lane < 16) ? wsum[lane] : 0;
            for (int d = 1; d < 16; d <<= 1) { int t = __shfl_up(w, d, 64); if (lane >= d) w += t; }
            if (lane < 16) wsum[lane] = w;
        }
        __syncthreads();
        int wprev = (wid > 0) ? wsum[wid-1] : 0;
        int carry = s_carry;
        if (i < n) off[i] = carry + wprev + (v - v0);
        __syncthreads();
        if (tid == 0) s_carry = carry + wsum[15];
        __syncthreads();
    }
    if (tid == 0) off[n] = s_carry;
}
__global__ void k_copy(const int* __restrict__ off, int* cur) {
    int i = blockIdx.x*256 + threadIdx.x;
    if (i < N_NODES) cur[i] = off[i];
}
__global__ void k_fill(const int* __restrict__ ei, int* cur, int* __restrict__ csrc) {
    int i = blockIdx.x*256 + threadIdx.x;
    if (i < N_EDGES) {
        int s = ei[i], d = ei[N_EDGES + i];
        int p = atomicAdd(&cur[d], 1);
        csrc[p] = s;
    } else if (i < N_EDGES + N_NODES) {
        int n = i - N_EDGES;
        int p = atomicAdd(&cur[n], 1);
        csrc[p] = n;
    }
}

// ---------------- bf16 conversion/transpose kernels ----------------
__global__ void k_cvt_x(const float* __restrict__ x, __hip_bfloat16* __restrict__ xp) {
    int i = blockIdx.x*256 + threadIdx.x;
    if (i >= N_NODES*KX) return;
    int n = i / KX, c = i - n*KX;
    float v = (c < F0c) ? x[(size_t)n*F0c + c] : 0.f;
    xp[i] = __float2bfloat16(v);
}
__global__ void k_cvt_w1t(const float* __restrict__ W1, __hip_bfloat16* __restrict__ W1t) {
    int i = blockIdx.x*256 + threadIdx.x;
    if (i >= 784*KX) return;
    int r = i / KX, k = i - r*KX;   // r = output col, k = input dim
    float v = (r < HC1 && k < F0c) ? W1[(size_t)k*HC1 + r] : 0.f;
    W1t[i] = __float2bfloat16(v);
}
__global__ void k_cvt_w2t(const float* __restrict__ W2, __hip_bfloat16* __restrict__ W2t) {
    int i = blockIdx.x*256 + threadIdx.x;
    if (i >= C2c*HSTR) return;
    int c = i / HSTR, k = i - c*HSTR;
    float v = (k < HC1) ? W2[(size_t)k*C2c + c] : 0.f;
    W2t[i] = __float2bfloat16(v);
}

// ---------------- GEMM1 (MFMA): xp[N,96] @ W1t[784,96]^T -> h[N,800] bf16 ----------------
__global__ void k_gemm1_mfma(const short* __restrict__ Xp, const short* __restrict__ W1t,
                             __hip_bfloat16* __restrict__ Hout) {
    int wave = threadIdx.x >> 6, lane = threadIdx.x & 63;
    int m16 = lane & 15, quad = lane >> 4;
    int r0 = blockIdx.x*64 + wave*16;
    int c0 = blockIdx.y*112;               // 7 col tiles of 16
    int rowc = min(r0 + m16, N_NODES-1);
    const short8* arow = (const short8*)(Xp + (size_t)rowc*KX);
    f32x4 acc[7];
    #pragma unroll
    for (int ct = 0; ct < 7; ct++) acc[ct] = (f32x4){0.f,0.f,0.f,0.f};
    #pragma unroll
    for (int kt = 0; kt < 3; kt++) {
        short8 af = arow[kt*4 + quad];
        #pragma unroll
        for (int ct = 0; ct < 7; ct++) {
            const short8* brow = (const short8*)(W1t + (size_t)(c0 + ct*16 + m16)*KX);
            short8 bf = brow[kt*4 + quad];
            acc[ct] = __builtin_amdgcn_mfma_f32_16x16x32_bf16(af, bf, acc[ct], 0, 0, 0);
        }
    }
    #pragma unroll
    for (int ct = 0; ct < 7; ct++) {
        int col = c0 + ct*16 + m16;
        if (col >= HC1) continue;
        #pragma unroll
        for (int r = 0; r < 4; r++) {
            int orow = r0 + quad*4 + r;
            if (orow < N_NODES) Hout[(size_t)orow*HSTR + col] = __float2bfloat16(acc[ct][r]);
        }
    }
}

// ---------------- GEMM2 (MFMA): out1[N,800] @ W2t[128,800]^T -> h2[N,128] f32 ----------------
__global__ void k_gemm2_mfma(const short* __restrict__ A, const short* __restrict__ Bt,
                             float* __restrict__ Cout) {
    int wave = threadIdx.x >> 6, lane = threadIdx.x & 63;
    int m16 = lane & 15, quad = lane >> 4;
    int r0 = blockIdx.x*64 + wave*16;
    int rowc = min(r0 + m16, N_NODES-1);
    const short8* arow = (const short8*)(A + (size_t)rowc*HSTR);
    f32x4 acc[8];
    #pragma unroll
    for (int ct = 0; ct < 8; ct++) acc[ct] = (f32x4){0.f,0.f,0.f,0.f};
    for (int kt = 0; kt < 25; kt++) {
        short8 af = arow[kt*4 + quad];
        #pragma unroll
        for (int ct = 0; ct < 8; ct++) {
            const short8* brow = (const short8*)(Bt + (size_t)(ct*16 + m16)*HSTR);
            short8 bf = brow[kt*4 + quad];
            acc[ct] = __builtin_amdgcn_mfma_f32_16x16x32_bf16(af, bf, acc[ct], 0, 0, 0);
        }
    }
    #pragma unroll
    for (int ct = 0; ct < 8; ct++) {
        #pragma unroll
        for (int r = 0; r < 4; r++) {
            int orow = r0 + quad*4 + r;
            if (orow < N_NODES) Cout[(size_t)orow*C2c + ct*16 + m16] = acc[ct][r];
        }
    }
}

// ---------------- attention logit precompute ----------------
__device__ __forceinline__ float bf_lo(unsigned u) { return __uint_as_float(u << 16); }
__device__ __forceinline__ float bf_hi(unsigned u) { return __uint_as_float(u & 0xffff0000u); }

__global__ void k_att1(const __hip_bfloat16* __restrict__ h, const float* __restrict__ a_src,
                       const float* __restrict__ a_dst, float* __restrict__ als,
                       float* __restrict__ ald) {
    int i = blockIdx.x*256 + threadIdx.x;
    if (i >= N_NODES*H1c) return;
    int n = i / H1c, hh = i - n*H1c;
    const unsigned* hp = (const unsigned*)((const unsigned short*)h + (size_t)n*HSTR + hh*F0c);
    const float* asv = a_src + hh*F0c;
    const float* adv = a_dst + hh*F0c;
    float s1 = 0.f, s2 = 0.f;
    #pragma unroll
    for (int c2 = 0; c2 < F0c/2; c2++) {
        unsigned u = hp[c2];
        float v0 = bf_lo(u), v1 = bf_hi(u);
        s1 += v0*asv[2*c2] + v1*asv[2*c2+1];
        s2 += v0*adv[2*c2] + v1*adv[2*c2+1];
    }
    als[i] = s1; ald[i] = s2;
}
__global__ void k_att2(const float* __restrict__ h, const float* __restrict__ a_src,
                       const float* __restrict__ a_dst, float* __restrict__ als,
                       float* __restrict__ ald) {
    int n = blockIdx.x*256 + threadIdx.x;
    if (n >= N_NODES) return;
    const float* hp = h + (size_t)n*C2c;
    float s1 = 0.f, s2 = 0.f;
    for (int c = 0; c < C2c; c++) { float v = hp[c]; s1 += v*a_src[c]; s2 += v*a_dst[c]; }
    als[n] = s1; ald[n] = s2;
}

// ---------------- GAT aggregation: one wave per dst node ----------------
// ACT: 0=elu, 1=relu. STRIDE = output/input row stride, PAD = zero-pad cols after H*C.
template<typename TI, typename TO, int H, int C, int ACT, int STRIDE, int PAD>
__global__ void k_agg(const TI* __restrict__ hbuf, const float* __restrict__ als,
                      const float* __restrict__ ald, const int* __restrict__ offs,
                      const int* __restrict__ csrc, const float* __restrict__ bias,
                      TO* __restrict__ out) {
    int dn = blockIdx.x;
    int lane = threadIdx.x;      // 64
    int s = offs[dn], e = offs[dn+1];
    int deg = e - s;
    __shared__ float ms[H], dinv_s[H];
    __shared__ float wexp[128*H];
    __shared__ int ssrc[128];
    if (deg <= 128) {
        for (int j = lane; j < deg; j += 64) ssrc[j] = csrc[s + j];
        __syncthreads();
        for (int idx = lane; idx < deg*H; idx += 64) {
            int j = idx / H, hh = idx - j*H;
            float al = als[(size_t)ssrc[j]*H + hh] + ald[(size_t)dn*H + hh];
            al = (al >= 0.f) ? al : 0.2f*al;
            wexp[idx] = al;
        }
        __syncthreads();
        if (lane < H) {
            float m = -1e30f;
            for (int j = 0; j < deg; j++) m = fmaxf(m, wexp[j*H + lane]);
            float den = 0.f;
            for (int j = 0; j < deg; j++) den += __expf(wexp[j*H + lane] - m);
            ms[lane] = m;
            dinv_s[lane] = 1.0f / (den + 1e-16f);
        }
        __syncthreads();
        for (int idx = lane; idx < deg*H; idx += 64) {
            int hh = idx - (idx / H)*H;
            wexp[idx] = __expf(wexp[idx] - ms[hh]) * dinv_s[hh];
        }
        __syncthreads();
        for (int hh = 0; hh < H; hh++) {
            for (int cb = 0; cb < C; cb += 64) {
                int c = cb + lane;
                if (c < C) {
                    float acc = 0.f;
                    for (int j = 0; j < deg; j++)
                        acc += wexp[j*H + hh] * ldf(&hbuf[(size_t)ssrc[j]*STRIDE + hh*C + c]);
                    float v = acc + bias[hh*C + c];
                    if (ACT == 0) v = (v > 0.f) ? v : (__expf(v) - 1.f);
                    else          v = fmaxf(v, 0.f);
                    stf(&out[(size_t)dn*STRIDE + hh*C + c], v);
                }
            }
        }
    } else {
        // fallback (deg > 128): recompute path, guaranteed correct
        if (lane < H) {
            float adv = ald[(size_t)dn*H + lane];
            float m = -1e30f;
            for (int j = s; j < e; j++) {
                int sj = csrc[j];
                float al = als[(size_t)sj*H + lane] + adv;
                al = (al >= 0.f) ? al : 0.2f*al;
                m = fmaxf(m, al);
            }
            float den = 0.f;
            for (int j = s; j < e; j++) {
                int sj = csrc[j];
                float al = als[(size_t)sj*H + lane] + adv;
                al = (al >= 0.f) ? al : 0.2f*al;
                den += __expf(al - m);
            }
            ms[lane] = m;
            dinv_s[lane] = 1.0f / (den + 1e-16f);
        }
        __syncthreads();
        for (int hh = 0; hh < H; hh++) {
            float m = ms[hh], dinv = dinv_s[hh];
            float adv = ald[(size_t)dn*H + hh];
            for (int cb = 0; cb < C; cb += 64) {
                int c = cb + lane;
                if (c < C) {
                    float acc = 0.f;
                    for (int j = s; j < e; j++) {
                        int sj = csrc[j];
                        float al = als[(size_t)sj*H + hh] + adv;
                        al = (al >= 0.f) ? al : 0.2f*al;
                        float alpha = __expf(al - m) * dinv;
                        acc += alpha * ldf(&hbuf[(size_t)sj*STRIDE + hh*C + c]);
                    }
                    float v = acc + bias[hh*C + c];
                    if (ACT == 0) v = (v > 0.f) ? v : (__expf(v) - 1.f);
                    else          v = fmaxf(v, 0.f);
                    stf(&out[(size_t)dn*STRIDE + hh*C + c], v);
                }
            }
        }
    }
    if (PAD > 0 && lane < PAD) stf(&out[(size_t)dn*STRIDE + H*C + lane], 0.f);
}

// ---------------- global max pool (batch sorted) ----------------
__global__ void k_pool(const float* __restrict__ hf, const int* __restrict__ batch,
                       float* __restrict__ g) {
    int b = blockIdx.x, tid = threadIdx.x;    // 128
    __shared__ int se[2];
    if (tid < 2) {
        int key = b + tid;
        int lo = 0, hi = N_NODES;
        while (lo < hi) { int mid = (lo+hi) >> 1; if (batch[mid] < key) lo = mid+1; else hi = mid; }
        se[tid] = lo;
    }
    __syncthreads();
    int s = se[0], e = se[1];
    float m = -1e30f;
    for (int n = s; n < e; n++) m = fmaxf(m, hf[(size_t)n*C2c + tid]);
    g[b*C2c + tid] = m;
}
__global__ void k_fcg(const float* __restrict__ g, const float* __restrict__ W,
                      const float* __restrict__ bias, float* __restrict__ xc) {
    int b = blockIdx.x, tid = threadIdx.x;    // 128
    __shared__ float gs[C2c];
    gs[tid] = g[b*C2c + tid];
    __syncthreads();
    float acc = bias[tid];
    for (int k = 0; k < C2c; k++) acc += gs[k] * W[k*C2c + tid];
    xc[b*256 + tid] = fmaxf(acc, 0.f);
}

// ---------------- conv path: bucket targets by vocab ----------------
__global__ void k_bucket(const int* __restrict__ target, int* __restrict__ ordered,
                         int* __restrict__ boff) {
    int b = blockIdx.x, tid = threadIdx.x;    // 256
    __shared__ int cnt[VOCABc];
    __shared__ int offs[VOCABc+1];
    __shared__ int cur[VOCABc];
    if (tid < VOCABc) cnt[tid] = 0;
    __syncthreads();
    for (int i = tid; i < SEQc; i += 256) atomicAdd(&cnt[target[(size_t)b*SEQc + i]], 1);
    __syncthreads();
    if (tid == 0) { offs[0] = 0; for (int v = 0; v < VOCABc; v++) offs[v+1] = offs[v] + cnt[v]; }
    __syncthreads();
    if (tid < VOCABc) cur[tid] = offs[tid];
    if (tid < VOCABc+1) boff[b*(VOCABc+1) + tid] = offs[tid];
    __syncthreads();
    for (int i = tid; i < SEQc; i += 256) {
        int t = target[(size_t)b*SEQc + i];
        int p = atomicAdd(&cur[t], 1);
        ordered[(size_t)b*SEQc + p] = i;
    }
}
__global__ void k_buildA(const float* __restrict__ convw, const int* __restrict__ ordered,
                         const int* __restrict__ boff, float* __restrict__ Amat) {
    int t = blockIdx.x, b = blockIdx.y;
    int tid = threadIdx.x;                // 256 = 32 o * 8 k
    int o = tid >> 3, k = tid & 7;
    int s = boff[b*(VOCABc+1) + t], e = boff[b*(VOCABc+1) + t + 1];
    const int* ord = ordered + (size_t)b*SEQc;
    float acc = 0.f;
    for (int j = s; j < e; j++) {
        int i = ord[j];
        acc += convw[((size_t)o*SEQc + i)*KWc + k];
    }
    Amat[(((size_t)b*NFc + o)*VOCABc + t)*KWc + k] = acc;
}
__global__ void k_conv(const float* __restrict__ Amat, const float* __restrict__ emb,
                       const float* __restrict__ convb, float* __restrict__ convout) {
    int b = blockIdx.x, tid = threadIdx.x;    // 128
    __shared__ float embs[VOCABc*EMBc];       // 13.3 KB
    __shared__ float arow[VOCABc*KWc];        // 832 B
    for (int i = tid; i < VOCABc*EMBc; i += 128) embs[i] = emb[i];
    __syncthreads();
    for (int o = 0; o < NFc; o++) {
        for (int i = tid; i < VOCABc*KWc; i += 128)
            arow[i] = Amat[((size_t)b*NFc + o)*(VOCABc*KWc) + i];
        __syncthreads();
        if (tid < LOUTc) {
            float acc = convb[o];
            for (int t = 0; t < VOCABc; t++) {
                #pragma unroll
                for (int k = 0; k < KWc; k++) acc += arow[t*KWc + k] * embs[t*EMBc + tid + k];
            }
            convout[(size_t)b*(NFc*LOUTc) + o*LOUTc + tid] = fmaxf(acc, 0.f);
        }
        __syncthreads();
    }
}
__global__ void k_fcxt(const float* __restrict__ convout, const float* __restrict__ W,
                       const float* __restrict__ bias, float* __restrict__ xc) {
    int b = blockIdx.x, tid = threadIdx.x;    // 128
    __shared__ float cs[NFc*LOUTc];           // 15.5 KB
    for (int i = tid; i < NFc*LOUTc; i += 128) cs[i] = convout[(size_t)b*(NFc*LOUTc) + i];
    __syncthreads();
    float acc = bias[tid];
    for (int j = 0; j < NFc*LOUTc; j++) acc += cs[j] * W[(size_t)j*C2c + tid];
    xc[b*256 + 128 + tid] = acc;
}

// ---------------- head MLP ----------------
__global__ void k_fc1(const float* __restrict__ xc, const float* __restrict__ W,
                      const float* __restrict__ bias, float* __restrict__ y1) {
    int b = blockIdx.x, tid = threadIdx.x;    // 256
    __shared__ float xs[256];
    xs[tid] = xc[b*256 + tid];
    __syncthreads();
    float a0 = bias[tid], a1 = bias[tid+256], a2 = bias[tid+512], a3 = bias[tid+768];
    for (int k = 0; k < 256; k++) {
        float xk = xs[k];
        const float* wr = W + (size_t)k*1024;
        a0 += xk*wr[tid]; a1 += xk*wr[tid+256]; a2 += xk*wr[tid+512]; a3 += xk*wr[tid+768];
    }
    y1[(size_t)b*1024 + tid      ] = fmaxf(a0, 0.f);
    y1[(size_t)b*1024 + tid + 256] = fmaxf(a1, 0.f);
    y1[(size_t)b*1024 + tid + 512] = fmaxf(a2, 0.f);
    y1[(size_t)b*1024 + tid + 768] = fmaxf(a3, 0.f);
}
__global__ void k_fc2(const float* __restrict__ y1, const float* __restrict__ W,
                      const float* __restrict__ bias, float* __restrict__ y2) {
    int b = blockIdx.x, tid = threadIdx.x;    // 256
    __shared__ float ys[1024];
    for (int i = tid; i < 1024; i += 256) ys[i] = y1[(size_t)b*1024 + i];
    __syncthreads();
    float acc = bias[tid];
    for (int k = 0; k < 1024; k++) acc += ys[k] * W[(size_t)k*256 + tid];
    y2[b*256 + tid] = fmaxf(acc, 0.f);
}
__global__ void k_out(const float* __restrict__ y2, const float* __restrict__ ow,
                      const float* __restrict__ ob, float* __restrict__ out) {
    int b = blockIdx.x, lane = threadIdx.x;   // 64
    float p = 0.f;
    for (int c = lane; c < 256; c += 64) p += y2[b*256 + c] * ow[c];
    for (int d = 32; d > 0; d >>= 1) p += __shfl_xor(p, d, 64);
    if (lane == 0) out[b] = p + ob[0];
}

extern "C" void kernel_launch(void* const* d_in, const int* in_sizes, int n_in,
                              void* d_out, int out_size, void* d_ws, size_t ws_size,
                              hipStream_t stream) {
    (void)in_sizes; (void)n_in; (void)out_size;
    if (ws_size < A_END) return;   // guard: clean numeric-fail if ws too small

    const float* x       = (const float*)d_in[0];
    const int*   ei      = (const int*)  d_in[1];
    const int*   batch   = (const int*)  d_in[2];
    const int*   target  = (const int*)  d_in[3];
    const float* W1      = (const float*)d_in[4];
    const float* a_src1  = (const float*)d_in[5];
    const float* a_dst1  = (const float*)d_in[6];
    const float* b1      = (const float*)d_in[7];
    const float* W2      = (const float*)d_in[8];
    const float* a_src2  = (const float*)d_in[9];
    const float* a_dst2  = (const float*)d_in[10];
    const float* b2      = (const float*)d_in[11];
    const float* fcg_w   = (const float*)d_in[12];
    const float* fcg_b   = (const float*)d_in[13];
    const float* emb     = (const float*)d_in[14];
    const float* conv_w  = (const float*)d_in[15];
    const float* conv_b  = (const float*)d_in[16];
    const float* fcxt_w  = (const float*)d_in[17];
    const float* fcxt_b  = (const float*)d_in[18];
    const float* fc1_w   = (const float*)d_in[19];
    const float* fc1_b   = (const float*)d_in[20];
    const float* fc2_w   = (const float*)d_in[21];
    const float* fc2_b   = (const float*)d_in[22];
    const float* out_w   = (const float*)d_in[23];
    const float* out_b   = (const float*)d_in[24];

    char* wsb = (char*)d_ws;
    __hip_bfloat16* hbuf = (__hip_bfloat16*)(wsb + A_HBUF);
    __hip_bfloat16* out1 = (__hip_bfloat16*)(wsb + A_OUT1);
    float* h2    = (float*)(wsb + A_H2);
    __hip_bfloat16* w2t  = (__hip_bfloat16*)(wsb + A_W2T);
    float* als1  = (float*)(wsb + A_ALS1);
    float* ald1  = (float*)(wsb + A_ALD1);
    float* als2  = (float*)(wsb + A_ALS2);
    float* ald2  = (float*)(wsb + A_ALD2);
    int*   deg   = (int*)  (wsb + A_DEG);
    int*   offs  = (int*)  (wsb + A_OFFS);
    int*   cur   = (int*)  (wsb + A_CUR);
    int*   csrc  = (int*)  (wsb + A_CSRC);
    float* g     = (float*)(wsb + A_G);
    float* xc    = (float*)(wsb + A_XC);
    float* y1    = (float*)(wsb + A_Y1);
    float* y2    = (float*)(wsb + A_Y2);
    int*   boff  = (int*)  (wsb + A_BOFF);
    // aliases (see layout comments for lifetime safety):
    float* hfin  = (float*)(wsb + A_HFIN);
    int*   ord   = (int*)  (wsb + A_ORD);
    float* Amat  = (float*)(wsb + A_AMAT);
    float* cvo   = (float*)(wsb + A_CVO);
    __hip_bfloat16* xpad = (__hip_bfloat16*)(wsb + A_XPAD);
    __hip_bfloat16* w1t  = (__hip_bfloat16*)(wsb + A_W1T);

    // CSR build
    k_deginit<<<(N_NODES+255)/256, 256, 0, stream>>>(deg);
    k_count  <<<(N_EDGES+255)/256, 256, 0, stream>>>(ei, deg);
    k_scan   <<<1, 1024, 0, stream>>>(deg, offs, N_NODES);
    k_copy   <<<(N_NODES+255)/256, 256, 0, stream>>>(offs, cur);
    k_fill   <<<(N_EDGES+N_NODES+255)/256, 256, 0, stream>>>(ei, cur, csrc);

    // bf16 conversions
    k_cvt_x  <<<(N_NODES*KX+255)/256, 256, 0, stream>>>(x, xpad);
    k_cvt_w1t<<<(784*KX+255)/256, 256, 0, stream>>>(W1, w1t);
    k_cvt_w2t<<<(C2c*HSTR+255)/256, 256, 0, stream>>>(W2, w2t);

    // GAT layer 1
    k_gemm1_mfma<<<dim3((N_NODES+63)/64, 7), 256, 0, stream>>>((const short*)xpad, (const short*)w1t, hbuf);
    k_att1<<<(N_NODES*H1c+255)/256, 256, 0, stream>>>(hbuf, a_src1, a_dst1, als1, ald1);
    k_agg<__hip_bfloat16, __hip_bfloat16, H1c, F0c, 0, HSTR, 20><<<N_NODES, 64, 0, stream>>>(
        hbuf, als1, ald1, offs, csrc, b1, out1);
    // ---- hbuf dead from here; xpad/w1t dead (region B now owned by out1) ----

    // GAT layer 2
    k_gemm2_mfma<<<dim3((N_NODES+63)/64, 1), 256, 0, stream>>>((const short*)out1, (const short*)w2t, h2);
    k_att2<<<(N_NODES+255)/256, 256, 0, stream>>>(h2, a_src2, a_dst2, als2, ald2);
    k_agg<float, float, 1, C2c, 1, C2c, 0><<<N_NODES, 64, 0, stream>>>(
        h2, als2, ald2, offs, csrc, b2, hfin);

    // pool + fc_g1 -> xc[:, 0:128]
    k_pool<<<BGRAPHS, 128, 0, stream>>>(hfin, batch, g);
    k_fcg <<<BGRAPHS, 128, 0, stream>>>(g, fcg_w, fcg_b, xc);

    // conv path -> xc[:, 128:256]
    k_bucket<<<BGRAPHS, 256, 0, stream>>>(target, ord, boff);
    k_buildA<<<dim3(VOCABc, BGRAPHS), 256, 0, stream>>>(conv_w, ord, boff, Amat);
    k_conv  <<<BGRAPHS, 128, 0, stream>>>(Amat, emb, conv_b, cvo);
    k_fcxt  <<<BGRAPHS, 128, 0, stream>>>(cvo, fcxt_w, fcxt_b, xc);

    // head MLP
    k_fc1<<<BGRAPHS, 256, 0, stream>>>(xc, fc1_w, fc1_b, y1);
    k_fc2<<<BGRAPHS, 256, 0, stream>>>(y1, fc2_w, fc2_b, y2);
    k_out<<<BGRAPHS, 64, 0, stream>>>(y2, out_w, out_b, (float*)d_out);
}